// Round 1
// baseline (103.853 us; speedup 1.0000x reference)
//
#include <hip/hip_runtime.h>
#include <math.h>

#define NPTS  8192
#define BATCH 2
#define CJ    512          // candidate chunk staged in LDS
#define IPT   8            // points per thread (register-resident)
#define TPB   256
// point slots: 2 dirs * 2 batches * 8192 = 32768
// points/block = TPB*IPT = 2048  -> grid.x = 16
// chunks = NPTS/CJ = 16          -> grid.y = 16  => 256 blocks, 4 waves each

__global__ __launch_bounds__(TPB) void chamfer_pairs(
    const float* __restrict__ pred, const float* __restrict__ gt,
    unsigned int* __restrict__ mins)
{
    __shared__ float4 tile[CJ];

    const int base  = blockIdx.x * (TPB * IPT);   // global point-slot base
    const int dir   = base >> 14;                 // 0: points=gt (dist1), 1: points=pred (dist2)
    const int b     = (base >> 13) & 1;
    const int ibase = base & (NPTS - 1);

    const float* pts  = (dir == 0 ? gt : pred) + (size_t)b * NPTS * 3;
    const float* cand = (dir == 0 ? pred : gt) + (size_t)b * NPTS * 3;

    // stage candidate chunk into LDS as (x, y, z, q=0.5*|c|^2)
    const int j0 = blockIdx.y * CJ;
    for (int jj = threadIdx.x; jj < CJ; jj += TPB) {
        float x = cand[(size_t)(j0 + jj) * 3 + 0];
        float y = cand[(size_t)(j0 + jj) * 3 + 1];
        float z = cand[(size_t)(j0 + jj) * 3 + 2];
        float q = 0.5f * (x * x + y * y + z * z);
        tile[jj] = make_float4(x, y, z, q);
    }

    // my IPT points, register-resident
    float px[IPT], py[IPT], pz[IPT], m[IPT];
#pragma unroll
    for (int k = 0; k < IPT; ++k) {
        int i = ibase + threadIdx.x + k * TPB;
        px[k] = pts[(size_t)i * 3 + 0];
        py[k] = pts[(size_t)i * 3 + 1];
        pz[k] = pts[(size_t)i * 3 + 2];
        m[k]  = 3.0e38f;
    }
    __syncthreads();

    // min over candidates of t = 0.5|c|^2 - p.c   (d^2 = |p|^2 + 2t)
#pragma unroll 4
    for (int j = 0; j < CJ; ++j) {
        float4 c = tile[j];            // broadcast ds_read_b128 (all lanes same addr)
#pragma unroll
        for (int k = 0; k < IPT; ++k) {
            float t = fmaf(-px[k], c.x, c.w);
            t = fmaf(-py[k], c.y, t);
            t = fmaf(-pz[k], c.z, t);
            m[k] = fminf(m[k], t);
        }
    }

#pragma unroll
    for (int k = 0; k < IPT; ++k) {
        float gsq = fmaf(px[k], px[k], fmaf(py[k], py[k], pz[k] * pz[k]));
        float d2  = fmaxf(fmaf(2.0f, m[k], gsq), 0.0f);   // >= 0 -> uint-monotone
        atomicMin(&mins[base + k * TPB + threadIdx.x], __float_as_uint(d2));
    }
}

__global__ __launch_bounds__(1024) void chamfer_reduce(
    const unsigned int* __restrict__ mins, float* __restrict__ out)
{
    float s = 0.f;
    for (int idx = threadIdx.x; idx < 2 * BATCH * NPTS; idx += 1024)
        s += sqrtf(__uint_as_float(mins[idx]));

    for (int off = 32; off > 0; off >>= 1)
        s += __shfl_down(s, off, 64);

    __shared__ float ws[16];
    const int wave = threadIdx.x >> 6, lane = threadIdx.x & 63;
    if (lane == 0) ws[wave] = s;
    __syncthreads();
    if (threadIdx.x == 0) {
        float t = 0.f;
        for (int w = 0; w < 16; ++w) t += ws[w];
        out[0] = t / (float)(BATCH * NPTS);
    }
}

extern "C" void kernel_launch(void* const* d_in, const int* in_sizes, int n_in,
                              void* d_out, int out_size, void* d_ws, size_t ws_size,
                              hipStream_t stream) {
    const float* pred = (const float*)d_in[0];
    const float* gt   = (const float*)d_in[1];
    unsigned int* mins = (unsigned int*)d_ws;   // 32768 * 4B = 128 KB

    hipMemsetAsync(mins, 0x7F, (size_t)2 * BATCH * NPTS * sizeof(unsigned int), stream);

    dim3 grid((2 * BATCH * NPTS) / (TPB * IPT), NPTS / CJ);
    chamfer_pairs<<<grid, TPB, 0, stream>>>(pred, gt, mins);
    chamfer_reduce<<<1, 1024, 0, stream>>>(mins, (float*)d_out);
}

// Round 2
// 79.649 us; speedup vs baseline: 1.3039x; 1.3039x over previous
//
#include <hip/hip_runtime.h>
#include <math.h>

#define NPTS  8192
#define BATCH 2
#define CJ    256          // candidate chunk staged in LDS (SoA)
#define IPT   4            // points per thread (register-resident)
#define TPB   256
// point slots: 2 dirs * 2 batches * 8192 = 32768
// points/block = TPB*IPT = 1024 -> grid.x = 32
// chunks = NPTS/CJ = 32         -> grid.y = 32  => 1024 blocks (4/CU, 16 waves/CU)

typedef float v2f __attribute__((ext_vector_type(2)));

__global__ __launch_bounds__(TPB) void chamfer_pairs(
    const float* __restrict__ pred, const float* __restrict__ gt,
    unsigned int* __restrict__ mins)
{
    __shared__ float xs[CJ], ys[CJ], zs[CJ], qs[CJ];   // SoA for float2 LDS loads

    const int base  = blockIdx.x * (TPB * IPT);   // global point-slot base
    const int dir   = base >> 14;                 // 0: points=gt (dist1), 1: points=pred (dist2)
    const int b     = (base >> 13) & 1;
    const int ibase = base & (NPTS - 1);

    const float* pts  = (dir == 0 ? gt : pred) + (size_t)b * NPTS * 3;
    const float* cand = (dir == 0 ? pred : gt) + (size_t)b * NPTS * 3;

    // stage candidate chunk: (x, y, z, q = 0.5*|c|^2), SoA
    const int j0 = blockIdx.y * CJ;
    for (int jj = threadIdx.x; jj < CJ; jj += TPB) {
        float x = cand[(size_t)(j0 + jj) * 3 + 0];
        float y = cand[(size_t)(j0 + jj) * 3 + 1];
        float z = cand[(size_t)(j0 + jj) * 3 + 2];
        xs[jj] = x; ys[jj] = y; zs[jj] = z;
        qs[jj] = 0.5f * (x * x + y * y + z * z);
    }

    float px[IPT], py[IPT], pz[IPT];
    v2f   m2[IPT];
#pragma unroll
    for (int k = 0; k < IPT; ++k) {
        int i = ibase + threadIdx.x + k * TPB;
        px[k] = pts[(size_t)i * 3 + 0];
        py[k] = pts[(size_t)i * 3 + 1];
        pz[k] = pts[(size_t)i * 3 + 2];
        m2[k] = (v2f)(3.0e38f);
    }
    __syncthreads();

    const v2f* xs2 = (const v2f*)xs;
    const v2f* ys2 = (const v2f*)ys;
    const v2f* zs2 = (const v2f*)zs;
    const v2f* qs2 = (const v2f*)qs;

    // min over candidate pairs of t = q - p.c  (d^2 = |p|^2 + 2t), packed fp32
#pragma unroll 4
    for (int j = 0; j < CJ / 2; ++j) {
        v2f cx = xs2[j], cy = ys2[j], cz = zs2[j], cq = qs2[j];  // broadcast ds_read_b64
#pragma unroll
        for (int k = 0; k < IPT; ++k) {
            v2f t = cq - cx * px[k];      // v_pk_fma_f32 (ffp-contract)
            t = t - cy * py[k];
            t = t - cz * pz[k];
            m2[k].x = fminf(m2[k].x, t.x);
            m2[k].y = fminf(m2[k].y, t.y);
        }
    }

#pragma unroll
    for (int k = 0; k < IPT; ++k) {
        float gsq = fmaf(px[k], px[k], fmaf(py[k], py[k], pz[k] * pz[k]));
        float t   = fminf(m2[k].x, m2[k].y);
        float d2  = fmaxf(fmaf(2.0f, t, gsq), 0.0f);   // >= 0 -> uint-monotone
        atomicMin(&mins[base + k * TPB + threadIdx.x], __float_as_uint(d2));
    }
}

__global__ __launch_bounds__(TPB) void chamfer_reduce(
    const unsigned int* __restrict__ mins, float* __restrict__ out)
{
    const int idx0 = blockIdx.x * 2048;
    float s = 0.f;
#pragma unroll
    for (int r = 0; r < 2048 / TPB; ++r)
        s += sqrtf(__uint_as_float(mins[idx0 + r * TPB + threadIdx.x]));

    for (int off = 32; off > 0; off >>= 1)
        s += __shfl_down(s, off, 64);

    __shared__ float ws[4];
    const int wave = threadIdx.x >> 6, lane = threadIdx.x & 63;
    if (lane == 0) ws[wave] = s;
    __syncthreads();
    if (threadIdx.x == 0) {
        float t = (ws[0] + ws[1]) + (ws[2] + ws[3]);
        atomicAdd(out, t * (1.0f / (float)(BATCH * NPTS)));
    }
}

extern "C" void kernel_launch(void* const* d_in, const int* in_sizes, int n_in,
                              void* d_out, int out_size, void* d_ws, size_t ws_size,
                              hipStream_t stream) {
    const float* pred = (const float*)d_in[0];
    const float* gt   = (const float*)d_in[1];
    unsigned int* mins = (unsigned int*)d_ws;   // 32768 * 4B = 128 KB

    hipMemsetAsync(mins, 0x7F, (size_t)2 * BATCH * NPTS * sizeof(unsigned int), stream);
    hipMemsetAsync(d_out, 0, sizeof(float), stream);

    dim3 grid((2 * BATCH * NPTS) / (TPB * IPT), NPTS / CJ);
    chamfer_pairs<<<grid, TPB, 0, stream>>>(pred, gt, mins);
    chamfer_reduce<<<(2 * BATCH * NPTS) / 2048, TPB, 0, stream>>>(mins, (float*)d_out);
}